// Round 4
// baseline (348.360 us; speedup 1.0000x reference)
//
#include <hip/hip_runtime.h>

#define LO 506      // L_out
#define LL 512      // L
#define CC 128      // C
#define FF 128      // F
#define KC 896      // K*C per output position
#define BK 32       // K-tile
#define NT 32       // x-panel k-tiles: 1024 floats = x[b, 2g:2g+8, :]
#define G0 28       // GEMM0 (l0) active for tiles [0, 28)
#define G1 4        // GEMM1 (l1) active for tiles [4, 32)
#define NB 253      // grid: one block per l-pair
#define XS 40       // Xs row stride bf16 (32+8 pad)
#define WS 40       // W row stride bf16

typedef __attribute__((ext_vector_type(8))) short short8;     // 8 bf16 = 4 VGPR
typedef __attribute__((ext_vector_type(4))) float floatx4;
typedef __attribute__((ext_vector_type(4))) unsigned int uintx4;
typedef unsigned short ushort_t;

static __device__ __forceinline__ ushort_t f2bf(float f) {    // RNE f32 -> bf16
    union { float f; unsigned int u; } c; c.f = f;
    unsigned int u = c.u;
    return (ushort_t)((u + 0x7fffu + ((u >> 16) & 1u)) >> 16);
}
static __device__ __forceinline__ unsigned int pk2(float a, float b) {
    return (unsigned int)f2bf(a) | ((unsigned int)f2bf(b) << 16);
}

// 2 output positions (l0=2g, l1=2g+1) per block, full 128 batches x 128 f.
// One 128x1024 x-panel feeds BOTH GEMMs (l1 reads panel k shifted by +128),
// so x load traffic halves vs 1-l blocks and A fragments are shared per tile.
// W[l0],W[l1] fetched exactly once by construction (nontemporal: pure stream).
// 253 blocks, 512 thr, 1 block/CU (VGPR ~170 under launch_bounds(512,2) cap 256).
__global__ __launch_bounds__(512, 2)
void local_block_kernel(const float* __restrict__ x,
                        const float* __restrict__ wg,
                        const float* __restrict__ bias,
                        const float* __restrict__ gamma,
                        const float* __restrict__ beta,
                        const float* __restrict__ mmean,
                        const float* __restrict__ mvar,
                        float* __restrict__ out)
{
    // ---- bijective XCD-chunk swizzle (nwg=253: chunks 32x5, 31x3) so the
    // ~32 co-resident blocks per XCD cover a contiguous l-range (x L2 reuse)
    const int bid = blockIdx.x;
    const int xcd = bid & 7;
    const int idx = bid >> 3;
    const int q8  = NB >> 3;              // 31
    const int r8  = NB & 7;               // 5
    const int g   = (xcd < r8) ? xcd * (q8 + 1) + idx
                               : r8 * (q8 + 1) + (xcd - r8) * q8 + idx;
    const int l0  = g * 2;
    const int l1  = l0 + 1;

    const int t    = threadIdx.x;         // 512 threads = 8 waves
    const int lane = t & 63;
    const int wave = t >> 6;
    const int q    = lane >> 4;           // k-group within wave
    const int l16  = lane & 15;
    const int wr   = wave >> 1;           // batch 32-block (0..3)
    const int wc   = wave & 1;            // f 64-half

    __shared__ __align__(16) ushort_t Xs [2][128 * XS];   // 20 KB
    __shared__ __align__(16) ushort_t W0s[2][128 * WS];   // 20 KB
    __shared__ __align__(16) ushort_t W1s[2][128 * WS];   // 20 KB (60 KB total)

    // ---- A staging: thread -> (row = t>>2, k-chunk = (t&3)*8); 8 floats
    const int am  = t >> 2;
    const int ak0 = (t & 3) * 8;
    const float* aptr = x + (size_t)am * (LL * CC) + l0 * CC + ak0;

    // ---- W staging: thread -> (f = t&127, k-group = (t>>7)*8); 8 strided dwords
    const int wf  = t & 127;
    const int wk  = (t >> 7) * 8;
    const float* wptr0 = wg + (size_t)l0 * (KC * FF) + wf;
    const float* wptr1 = wg + (size_t)l1 * (KC * FF) + wf;

    floatx4 acc0[2][4] = {};              // l0 accumulators (32 VGPR)
    floatx4 acc1[2][4] = {};              // l1 accumulators (32 VGPR)

    floatx4 arg0[2], arg1[2];             // 2-deep A prefetch
    float   w0r0[8], w0r1[8];             // 2-deep W[l0] prefetch
    float   w1r0[8], w1r1[8];             // 2-deep W[l1] prefetch

#define LOAD_A(AR, KT) { const float* p = aptr + (KT) * BK;                     \
        AR[0] = *(const floatx4*)(p);                                           \
        AR[1] = *(const floatx4*)(p + 4); }

#define LOAD_W(WR, PTR, KOFF) { const float* p = (PTR) + (size_t)((KOFF) + wk) * FF; \
        _Pragma("unroll") for (int j = 0; j < 8; ++j)                           \
            WR[j] = __builtin_nontemporal_load(p + j * FF); }

#define STAGE_A(S, AR) {                                                        \
        uintx4 av = { pk2(AR[0].x, AR[0].y), pk2(AR[0].z, AR[0].w),             \
                      pk2(AR[1].x, AR[1].y), pk2(AR[1].z, AR[1].w) };           \
        *(uintx4*)&Xs[S][am * XS + ak0] = av; }

#define STAGE_W(S, DST, WR) {                                                   \
        uintx4 wv = { pk2(WR[0], WR[1]), pk2(WR[2], WR[3]),                     \
                      pk2(WR[4], WR[5]), pk2(WR[6], WR[7]) };                   \
        *(uintx4*)&DST[S][wf * WS + wk] = wv; }

    // LDS-only drain barrier: prefetch global loads stay in flight (no vmcnt)
#define BAR() {                                                                 \
        asm volatile("s_waitcnt lgkmcnt(0)" ::: "memory");                      \
        __builtin_amdgcn_s_barrier();                                           \
        asm volatile("" ::: "memory"); }

#define GEMM(S, SRC, ACC, AF) {                                                 \
        short8 bfr[4];                                                          \
        _Pragma("unroll") for (int ni = 0; ni < 4; ++ni)                        \
            bfr[ni] = *(const short8*)&SRC[S][(wc*64 + ni*16 + l16) * WS + q*8];\
        _Pragma("unroll") for (int mi = 0; mi < 2; ++mi)                        \
            _Pragma("unroll") for (int ni = 0; ni < 4; ++ni)                    \
                ACC[mi][ni] = __builtin_amdgcn_mfma_f32_16x16x32_bf16(          \
                    AF[mi], bfr[ni], ACC[mi][ni], 0, 0, 0); }

#define LOAD_AF(S, AF) {                                                        \
        _Pragma("unroll") for (int mi = 0; mi < 2; ++mi)                        \
            AF[mi] = *(const short8*)&Xs[S][(wr*32 + mi*16 + l16) * XS + q*8]; }

    LOAD_A(arg0, 0); LOAD_W(w0r0, wptr0, 0 * BK);
    LOAD_A(arg1, 1); LOAD_W(w0r1, wptr0, 1 * BK);
    // w1r* first staged at kt=4; loaded during the kt=2 iteration.

    for (int kt = 0; kt < NT; kt += 2) {
        const bool p0 = (kt < G0);        // l0-GEMM active for this tile pair
        const bool p1 = (kt >= G1);       // l1-GEMM active for this tile pair

        // ---- tile kt -> buffer 0
        STAGE_A(0, arg0);
        if (p0) STAGE_W(0, W0s, w0r0);
        if (p1) STAGE_W(0, W1s, w1r0);
        if (kt + 2 < NT) LOAD_A(arg0, kt + 2);
        if (kt + 2 < G0) LOAD_W(w0r0, wptr0, (kt + 2) * BK);
        if (kt + 2 >= G1) LOAD_W(w1r0, wptr1, (kt + 2) * BK - 128);
        BAR();
        {
            short8 af[2]; LOAD_AF(0, af);
            if (p0) GEMM(0, W0s, acc0, af);
            if (p1) GEMM(0, W1s, acc1, af);
        }

        // ---- tile kt+1 -> buffer 1
        STAGE_A(1, arg1);
        if (p0) STAGE_W(1, W0s, w0r1);
        if (p1) STAGE_W(1, W1s, w1r1);
        if (kt + 3 < NT) LOAD_A(arg1, kt + 3);
        if (kt + 3 < G0) LOAD_W(w0r1, wptr0, (kt + 3) * BK);
        if (kt + 3 >= G1) LOAD_W(w1r1, wptr1, (kt + 3) * BK - 128);
        BAR();
        {
            short8 af[2]; LOAD_AF(1, af);
            if (p0) GEMM(1, W0s, acc0, af);
            if (p1) GEMM(1, W1s, acc1, af);
        }
    }

    // ---- epilogue: fold bias + BN per f (bias differs per l), relu, nt store
#pragma unroll
    for (int ni = 0; ni < 4; ++ni) {
        int f = wc*64 + ni*16 + l16;
        float inv  = gamma[f] * rsqrtf(mvar[f] + 1e-3f);
        float bcom = beta[f] - mmean[f] * inv;
        float off0 = bias[l0 * FF + f] * inv + bcom;
        float off1 = bias[l1 * FF + f] * inv + bcom;
#pragma unroll
        for (int mi = 0; mi < 2; ++mi) {
#pragma unroll
            for (int rg = 0; rg < 4; ++rg) {
                int b = wr*32 + mi*16 + q*4 + rg;   // C/D: row=(lane>>4)*4+reg
                float v0 = acc0[mi][ni][rg] * inv + off0;
                float v1 = acc1[mi][ni][rg] * inv + off1;
                __builtin_nontemporal_store(fmaxf(v0, 0.0f),
                    &out[((size_t)b * LO + l0) * FF + f]);
                __builtin_nontemporal_store(fmaxf(v1, 0.0f),
                    &out[((size_t)b * LO + l1) * FF + f]);
            }
        }
    }
#undef LOAD_A
#undef LOAD_W
#undef STAGE_A
#undef STAGE_W
#undef BAR
#undef GEMM
#undef LOAD_AF
}

extern "C" void kernel_launch(void* const* d_in, const int* in_sizes, int n_in,
                              void* d_out, int out_size, void* d_ws, size_t ws_size,
                              hipStream_t stream) {
    const float* x     = (const float*)d_in[0];
    const float* w     = (const float*)d_in[1];
    const float* bias  = (const float*)d_in[2];
    const float* gamma = (const float*)d_in[3];
    const float* beta  = (const float*)d_in[4];
    const float* mmean = (const float*)d_in[5];
    const float* mvar  = (const float*)d_in[6];
    float* out = (float*)d_out;

    local_block_kernel<<<dim3(NB), dim3(512), 0, stream>>>(
        x, w, bias, gamma, beta, mmean, mvar, out);
}

// Round 5
// 347.924 us; speedup vs baseline: 1.0013x; 1.0013x over previous
//
#include <hip/hip_runtime.h>
#include <hip/hip_bf16.h>

#define LO 506      // L_out
#define LL 512      // L
#define CC 128      // C
#define FF 128      // F
#define KC 896      // K*C (reduction dim)
#define BK 32       // K-tile
#define NK 28       // 896/32
#define XS 40       // Xs row stride in bf16 (32 + 8 pad; 80 B rows: 16B-aligned b128, 2-way banks = free)
#define WS 40       // Wt row stride in bf16

typedef __attribute__((ext_vector_type(8))) short short8;     // 8 bf16 = 4 VGPR (MFMA operand)
typedef __attribute__((ext_vector_type(4))) float floatx4;    // MFMA acc / float4 load
typedef __attribute__((ext_vector_type(4))) unsigned int uintx4;
typedef unsigned short ushort_t;

// Native RNE f32->bf16 via __float2bfloat16: the backend fuses adjacent pairs
// into v_cvt_pk_bf16_f32 (1 instr / 2 values) vs ~8 VALU ops for the manual
// bit-twiddle. memcpy extraction is layout-agnostic across ROCm headers.
static __device__ __forceinline__ unsigned int pk2(float a, float b) {
    __hip_bfloat16 ha = __float2bfloat16(a);
    __hip_bfloat16 hb = __float2bfloat16(b);
    unsigned short ua, ub;
    __builtin_memcpy(&ua, &ha, 2);
    __builtin_memcpy(&ub, &hb, 2);
    return (unsigned int)ua | ((unsigned int)ub << 16);
}

// grid = 506, one block per l, 512 threads = 8 waves, full 128b x 128f tile.
// Structure = R3 champion (347.2 us): bijective XCD-chunk swizzle, LDS
// double-buffer (one barrier/tile), 2-deep register prefetch, LDS-only-drain
// barriers (global loads stay in flight), nontemporal W loads / out stores.
// This round's single change: native cvt_pk staging conversion.
__global__ __launch_bounds__(512, 4)
void local_block_kernel(const float* __restrict__ x,
                        const float* __restrict__ wg,
                        const float* __restrict__ bias,
                        const float* __restrict__ gamma,
                        const float* __restrict__ beta,
                        const float* __restrict__ mmean,
                        const float* __restrict__ mvar,
                        float* __restrict__ out)
{
    // ---- bijective XCD-chunk swizzle (nwg=506, 8 XCDs: chunks 64,64,63x6)
    const int bid = blockIdx.x;
    const int xcd = bid & 7;
    const int idx = bid >> 3;
    const int q8  = LO >> 3;              // 63
    const int r8  = LO & 7;               // 2
    const int l   = (xcd < r8) ? xcd * (q8 + 1) + idx
                               : r8 * (q8 + 1) + (xcd - r8) * q8 + idx;

    const int t    = threadIdx.x;         // 512 threads = 8 waves
    const int lane = t & 63;
    const int wave = t >> 6;              // 0..7
    const int q    = lane >> 4;           // quad within wave (k-group)
    const int l16  = lane & 15;
    const int wr   = wave >> 1;           // wave row: batch 32-block (0..3)
    const int wc   = wave & 1;            // wave col: f 64-half

    __shared__ __align__(16) ushort_t Xs[2][128 * XS];   // 2 x 10 KB
    __shared__ __align__(16) ushort_t Wt[2][128 * WS];   // 2 x 10 KB  (40 KB total)

    // ---- A staging map: thread -> (row = t>>2, k-chunk = (t&3)*8); 8 floats = 2 float4
    const int am  = t >> 2;
    const int ak0 = (t & 3) * 8;
    const float* aptr = x + (size_t)am * (LL * CC) + l * CC + ak0;

    // ---- W staging map: thread -> (f = t&127, k 8-group = (t>>7)*8); 8 strided dword loads
    const int wf  = t & 127;
    const int wk  = (t >> 7) * 8;         // 0,8,16,24
    const float* wptr = wg + (size_t)l * (KC * FF) + wf;

    floatx4 acc[2][4] = {};               // 32 fp32 accumulators

    floatx4 areg0[2], areg1[2];           // 2-deep A prefetch (8+8 VGPR)
    float   wreg0[8], wreg1[8];           // 2-deep W prefetch (8+8 VGPR)

#define LOAD_A(AR, KT) { const float* p = aptr + (KT) * BK;                     \
        AR[0] = *(const floatx4*)(p);                                           \
        AR[1] = *(const floatx4*)(p + 4); }

#define LOAD_W(WR, KT) { const float* p = wptr + (size_t)((KT) * BK + wk) * FF; \
        _Pragma("unroll") for (int j = 0; j < 8; ++j)                           \
            WR[j] = __builtin_nontemporal_load(p + j * FF); }

#define STAGE(S, AR, WR) {                                                      \
        uintx4 av = { pk2(AR[0].x, AR[0].y), pk2(AR[0].z, AR[0].w),             \
                      pk2(AR[1].x, AR[1].y), pk2(AR[1].z, AR[1].w) };           \
        *(uintx4*)&Xs[S][am * XS + ak0] = av;                                   \
        uintx4 wv = { pk2(WR[0], WR[1]), pk2(WR[2], WR[3]),                     \
                      pk2(WR[4], WR[5]), pk2(WR[6], WR[7]) };                   \
        *(uintx4*)&Wt[S][wf * WS + wk] = wv; }

    // Barrier with LDS-only drain: own ds_writes complete (lgkmcnt), then
    // s_barrier; memory-clobber asms fence LDS ops on both sides so no
    // ds_read/ds_write crosses. vmcnt untouched -> prefetch stays in flight.
#define BAR() {                                                                 \
        asm volatile("s_waitcnt lgkmcnt(0)" ::: "memory");                      \
        __builtin_amdgcn_s_barrier();                                           \
        asm volatile("" ::: "memory"); }

#define COMPUTE(S) {                                                            \
        short8 af[2], bfr[4];                                                   \
        _Pragma("unroll") for (int mi = 0; mi < 2; ++mi)                        \
            af[mi] = *(const short8*)&Xs[S][(wr*32 + mi*16 + l16) * XS + q*8];  \
        _Pragma("unroll") for (int ni = 0; ni < 4; ++ni)                        \
            bfr[ni] = *(const short8*)&Wt[S][(wc*64 + ni*16 + l16) * WS + q*8]; \
        _Pragma("unroll") for (int mi = 0; mi < 2; ++mi)                        \
            _Pragma("unroll") for (int ni = 0; ni < 4; ++ni)                    \
                acc[mi][ni] = __builtin_amdgcn_mfma_f32_16x16x32_bf16(          \
                    af[mi], bfr[ni], acc[mi][ni], 0, 0, 0); }

    LOAD_A(areg0, 0); LOAD_W(wreg0, 0);
    LOAD_A(areg1, 1); LOAD_W(wreg1, 1);

    for (int kt = 0; kt < NK; kt += 2) {
        // ---- tile kt -> LDS buffer 0
        STAGE(0, areg0, wreg0);
        if (kt + 2 < NK) { LOAD_A(areg0, kt + 2); LOAD_W(wreg0, kt + 2); }
        BAR();
        COMPUTE(0);
        // ---- tile kt+1 -> LDS buffer 1 (safe: other waves still reading buf0 only)
        STAGE(1, areg1, wreg1);
        if (kt + 3 < NK) { LOAD_A(areg1, kt + 3); LOAD_W(wreg1, kt + 3); }
        BAR();
        COMPUTE(1);
    }

    // ---- epilogue: fold bias + BN into per-f scale/offset, relu, nontemporal store
#pragma unroll
    for (int ni = 0; ni < 4; ++ni) {
        int f = wc*64 + ni*16 + l16;
        float inv = gamma[f] * rsqrtf(mvar[f] + 1e-3f);
        float off = bias[l * FF + f] * inv + beta[f] - mmean[f] * inv;
#pragma unroll
        for (int mi = 0; mi < 2; ++mi) {
#pragma unroll
            for (int rg = 0; rg < 4; ++rg) {
                int b = wr*32 + mi*16 + q*4 + rg;   // C/D: row=(lane>>4)*4+reg
                float v = acc[mi][ni][rg] * inv + off;
                __builtin_nontemporal_store(fmaxf(v, 0.0f),
                    &out[((size_t)b * LO + l) * FF + f]);
            }
        }
    }
#undef LOAD_A
#undef LOAD_W
#undef STAGE
#undef BAR
#undef COMPUTE
}

extern "C" void kernel_launch(void* const* d_in, const int* in_sizes, int n_in,
                              void* d_out, int out_size, void* d_ws, size_t ws_size,
                              hipStream_t stream) {
    const float* x     = (const float*)d_in[0];
    const float* w     = (const float*)d_in[1];
    const float* bias  = (const float*)d_in[2];
    const float* gamma = (const float*)d_in[3];
    const float* beta  = (const float*)d_in[4];
    const float* mmean = (const float*)d_in[5];
    const float* mvar  = (const float*)d_in[6];
    float* out = (float*)d_out;

    local_block_kernel<<<dim3(LO), dim3(512), 0, stream>>>(
        x, w, bias, gamma, beta, mmean, mvar, out);
}